// Round 9
// baseline (513.197 us; speedup 1.0000x reference)
//
#include <hip/hip_runtime.h>
#include <hip/hip_bf16.h>
#include <cstdint>
#include <cstddef>

#define B_   128
#define T_   50
#define M_   4
#define D_   64
#define K_   64
#define L_   16
#define NIT  100001
#define NBP3 512
#define CHUNK3 196     /* 512*196 = 100352 >= NIT */
#define NCH3 7         /* ceil(196/32) */
#define PSTRIDE 8320   /* 8192 p-words + 128 srun words per block slice */

typedef unsigned short u16;
typedef unsigned int   u32;
typedef __attribute__((ext_vector_type(8))) short short8;
typedef __attribute__((ext_vector_type(4))) short short4v;
typedef __attribute__((ext_vector_type(4))) float f32x4;

__device__ __forceinline__ float bf2f(u16 v){ u32 u = ((u32)v)<<16; float f; __builtin_memcpy(&f,&u,4); return f; }
__device__ __forceinline__ u16 f2bf(float f){
  u32 u; __builtin_memcpy(&u,&f,4);
  u32 r = (u + 0x7FFFu + ((u>>16)&1u)) >> 16;
  return (u16)r;
}
__device__ __forceinline__ float fexp(float x){ return __builtin_amdgcn_exp2f(x*1.4426950408889634f); }
__device__ __forceinline__ float fsig(float x){ return __builtin_amdgcn_rcpf(1.0f + fexp(-x)); }
__device__ __forceinline__ float ftanh(float x){ return 1.0f - 2.0f*__builtin_amdgcn_rcpf(1.0f + fexp(2.0f*x)); }
__device__ __forceinline__ void unpack8(const u32* s, short8& h, short8& l){
  #pragma unroll
  for (int q=0;q<8;q++){ h[q]=(short)(s[q]&0xFFFFu); l[q]=(short)(s[q]>>16); }
}

#define MFMA32(A,Bv,C) __builtin_amdgcn_mfma_f32_16x16x32_bf16(A,Bv,C,0,0,0)

#if __has_builtin(__builtin_amdgcn_mfma_f32_16x16x16bf16_1k)
__device__ __forceinline__ f32x4 mfma16(short4v a, short4v b, f32x4 c){
  return __builtin_amdgcn_mfma_f32_16x16x16bf16_1k(a,b,c,0,0,0);
}
#elif __has_builtin(__builtin_amdgcn_mfma_f32_16x16x16_bf16)
__device__ __forceinline__ f32x4 mfma16(short4v a, short4v b, f32x4 c){
  return __builtin_amdgcn_mfma_f32_16x16x16_bf16(a,b,c,0,0,0);
}
#else
__device__ __forceinline__ f32x4 mfma16(short4v a, short4v b, f32x4 c){
  asm("v_mfma_f32_16x16x16_bf16 %0, %1, %2, %0" : "+v"(c) : "v"(a), "v"(b));
  return c;
}
#endif

// ---------------- prep x: embed+mask, split fp32 -> bf16 hi/lo, layout [m][t*128+b][64] ----------------
__global__ __launch_bounds__(256) void k_prep_x(const int* __restrict__ s0, const int* __restrict__ s1,
  const int* __restrict__ s2, const int* __restrict__ s3, const float* __restrict__ E,
  u16* __restrict__ xh, u16* __restrict__ xl)
{
  int id = blockIdx.x*256 + threadIdx.x;
  int e8 = id & 7;
  int rm = id >> 3;
  int m = rm / 6400; int r = rm - m*6400;
  int t = r >> 7, b = r & 127;
  const int* sq = (m==0)? s0 : (m==1)? s1 : (m==2)? s2 : s3;
  int idx = sq[b*T_ + t];
  float sc = (idx==0)? 0.0f : 1.0f;
  const float4* ep = (const float4*)(E + (size_t)idx*64 + e8*8);
  float4 v0 = ep[0], v1 = ep[1];
  float vals[8] = {v0.x,v0.y,v0.z,v0.w,v1.x,v1.y,v1.z,v1.w};
  u32 hw[4], lw[4];
  #pragma unroll
  for (int q=0;q<4;q++){
    float f0 = vals[2*q]*sc, f1 = vals[2*q+1]*sc;
    u16 h0 = f2bf(f0), h1 = f2bf(f1);
    u16 l0 = f2bf(f0 - bf2f(h0)), l1 = f2bf(f1 - bf2f(h1));
    hw[q] = (u32)h0 | ((u32)h1<<16);
    lw[q] = (u32)l0 | ((u32)l1<<16);
  }
  size_t off = (size_t)rm*64 + e8*8;
  uint4 hv; hv.x=hw[0]; hv.y=hw[1]; hv.z=hw[2]; hv.w=hw[3];
  uint4 lv; lv.x=lw[0]; lv.y=lw[1]; lv.z=lw[2]; lv.w=lw[3];
  *(uint4*)(xh + off) = hv;
  *(uint4*)(xl + off) = lv;
}

// ---------------- prep W: transpose Wx[m][d][g] -> [m][g][d], split bf16 hi/lo ----------------
__global__ __launch_bounds__(256) void k_prep_w(const float* __restrict__ Wx,
  u16* __restrict__ wh, u16* __restrict__ wl)
{
  __shared__ float tl[64][65];
  int m = blockIdx.x / 48, gt = blockIdx.x % 48;
  for (int it=0; it<16; ++it){
    int li = threadIdx.x + it*256;
    int dl = li >> 6, gl = li & 63;
    tl[dl][gl] = Wx[((size_t)m*64 + dl)*3072 + gt*64 + gl];
  }
  __syncthreads();
  for (int it=0; it<2; ++it){
    int unit = threadIdx.x + it*256;
    int gl = unit >> 3, d8 = unit & 7;
    u32 hw[4], lw[4];
    #pragma unroll
    for (int q=0;q<4;q++){
      float f0 = tl[d8*8+2*q][gl], f1 = tl[d8*8+2*q+1][gl];
      u16 h0 = f2bf(f0), h1 = f2bf(f1);
      u16 l0 = f2bf(f0 - bf2f(h0)), l1 = f2bf(f1 - bf2f(h1));
      hw[q] = (u32)h0 | ((u32)h1<<16);
      lw[q] = (u32)l0 | ((u32)l1<<16);
    }
    size_t off = ((size_t)m*3072 + gt*64 + gl)*64 + d8*8;
    uint4 hv; hv.x=hw[0]; hv.y=hw[1]; hv.z=hw[2]; hv.w=hw[3];
    uint4 lv; lv.x=lw[0]; lv.y=lw[1]; lv.z=lw[2]; lv.w=lw[3];
    *(uint4*)(wh + off) = hv;
    *(uint4*)(wl + off) = lv;
  }
}

// ---------------- fused GRU (round-4 proven, FROZEN): unroll-2 A/B pipeline, scalar f2bf packing ----------------
// PASS=1: C=0, write N1.  PASS=2: C=N1*r1, write N2.  PASS=3: C=N1*r1+N2*r2, no N write.
template<int PASS>
__global__ __launch_bounds__(256,2) void k_gru_mfma(
  const u16* __restrict__ xh, const u16* __restrict__ xl,
  const u16* __restrict__ wh, const u16* __restrict__ wl,
  const float* __restrict__ Wh, const float* __restrict__ bx, const float* __restrict__ bhp,
  const float* __restrict__ rp1, const float* __restrict__ rp2,
  const u16* __restrict__ Nr1, const u16* __restrict__ Nr2,
  u16* __restrict__ Nw, float* __restrict__ behE)
{
  int tid = threadIdx.x;
  int lane = tid & 63;
  int n16 = lane & 15, quad = lane >> 4;
  int j0 = quad*4;
  int wid = blockIdx.x*4 + (tid>>6);          // [0,2048)
  int bt = wid & 7, k = (wid>>3)&63, m = wid>>9;
  int b = bt*16 + n16;

  // Wx A-fragments (rows g = gate*1024 + k*16 + [0,16))
  short8 WxH[3][2], WxL[3][2];
  #pragma unroll
  for (int g=0; g<3; ++g){
    int grow = g*1024 + k*16 + n16;
    #pragma unroll
    for (int c=0; c<2; ++c){
      size_t off = ((size_t)(m*3072 + grow))*64 + c*32 + quad*8;
      WxH[g][c] = *(const short8*)(wh + off);
      WxL[g][c] = *(const short8*)(wl + off);
    }
  }
  // Wh A-fragments, split bf16: A[m=n16][k=quad*4+i] = Wh[l=quad*4+i][g*16+n16]
  const float* whp = Wh + ((size_t)(m*64+k)*16)*48;
  short4v WhH[3], WhL[3];
  #pragma unroll
  for (int g=0; g<3; ++g){
    short4v hhv, llv;
    #pragma unroll
    for (int i=0;i<4;i++){
      float w = whp[(j0+i)*48 + g*16 + n16];
      u16 hbits = f2bf(w);
      hhv[i] = (short)hbits;
      llv[i] = (short)f2bf(w - bf2f(hbits));
    }
    WhH[g]=hhv; WhL[g]=llv;
  }
  // biases: r,z fold bh into gi acc init; n keeps bh_n in gh acc init
  float biasv[3][4], bhn[4];
  #pragma unroll
  for (int g=0; g<3; ++g)
    #pragma unroll
    for (int rg=0; rg<4; ++rg){
      int j = j0+rg;
      float tb = bx[m*3072 + g*1024 + k*16 + j];
      if (g<2) tb += bhp[(m*64+k)*48 + g*16 + j];
      biasv[g][rg] = tb;
    }
  #pragma unroll
  for (int rg=0; rg<4; ++rg) bhn[rg] = bhp[(m*64+k)*48 + 32 + j0 + rg];

  float rv1[4]={0.f,0.f,0.f,0.f}, rv2[4]={0.f,0.f,0.f,0.f};
  if (PASS>=2){
    float4 q = *(const float4*)(rp1 + ((size_t)b*64+k)*16 + j0);
    rv1[0]=q.x; rv1[1]=q.y; rv1[2]=q.z; rv1[3]=q.w;
  }
  if (PASS==3){
    float4 q = *(const float4*)(rp2 + ((size_t)b*64+k)*16 + j0);
    rv2[0]=q.x; rv2[1]=q.y; rv2[2]=q.z; rv2[3]=q.w;
  }

  size_t xrow  = ((size_t)m*6400 + bt*16 + n16)*64 + quad*8;
  size_t nbase = ((size_t)(m*64+k))*102400 + (size_t)b*16 + j0;

  short4v hH = {0,0,0,0}, hL = {0,0,0,0};
  float hprev[4] = {0.f,0.f,0.f,0.f};

  // double-buffer registers
  short8 A0,A1,A2,A3, Bb0,Bb1,Bb2,Bb3;
  uint2 AN1={0,0}, AN2={0,0}, BN1={0,0}, BN2={0,0};

#define LOADA(tt) { size_t xo = xrow + (size_t)(tt)*8192; \
  A0 = *(const short8*)(xh + xo); A1 = *(const short8*)(xh + xo + 32); \
  A2 = *(const short8*)(xl + xo); A3 = *(const short8*)(xl + xo + 32); \
  if (PASS>=2) AN1 = *(const uint2*)(Nr1 + nbase + (size_t)(tt)*2048); \
  if (PASS==3) AN2 = *(const uint2*)(Nr2 + nbase + (size_t)(tt)*2048); }
#define LOADB(tt) { size_t xo = xrow + (size_t)(tt)*8192; \
  Bb0 = *(const short8*)(xh + xo); Bb1 = *(const short8*)(xh + xo + 32); \
  Bb2 = *(const short8*)(xl + xo); Bb3 = *(const short8*)(xl + xo + 32); \
  if (PASS>=2) BN1 = *(const uint2*)(Nr1 + nbase + (size_t)(tt)*2048); \
  if (PASS==3) BN2 = *(const uint2*)(Nr2 + nbase + (size_t)(tt)*2048); }

#define GRU_STEP(tt, X0,X1,X2,X3, NV1, NV2) { \
  f32x4 giA0 = {biasv[0][0], biasv[0][1], biasv[0][2], biasv[0][3]}; \
  f32x4 giA1 = {biasv[1][0], biasv[1][1], biasv[1][2], biasv[1][3]}; \
  f32x4 giA2 = {biasv[2][0], biasv[2][1], biasv[2][2], biasv[2][3]}; \
  giA0 = MFMA32(WxH[0][0], X0, giA0); giA1 = MFMA32(WxH[1][0], X0, giA1); giA2 = MFMA32(WxH[2][0], X0, giA2); \
  giA0 = MFMA32(WxH[0][1], X1, giA0); giA1 = MFMA32(WxH[1][1], X1, giA1); giA2 = MFMA32(WxH[2][1], X1, giA2); \
  giA0 = MFMA32(WxL[0][0], X0, giA0); giA1 = MFMA32(WxL[1][0], X0, giA1); giA2 = MFMA32(WxL[2][0], X0, giA2); \
  giA0 = MFMA32(WxL[0][1], X1, giA0); giA1 = MFMA32(WxL[1][1], X1, giA1); giA2 = MFMA32(WxL[2][1], X1, giA2); \
  giA0 = MFMA32(WxH[0][0], X2, giA0); giA1 = MFMA32(WxH[1][0], X2, giA1); giA2 = MFMA32(WxH[2][0], X2, giA2); \
  giA0 = MFMA32(WxH[0][1], X3, giA0); giA1 = MFMA32(WxH[1][1], X3, giA1); giA2 = MFMA32(WxH[2][1], X3, giA2); \
  f32x4 ghr = {0.f,0.f,0.f,0.f}, ghz = {0.f,0.f,0.f,0.f}; \
  f32x4 ghn = {bhn[0], bhn[1], bhn[2], bhn[3]}; \
  ghr = mfma16(WhH[0], hH, ghr); ghz = mfma16(WhH[1], hH, ghz); ghn = mfma16(WhH[2], hH, ghn); \
  ghr = mfma16(WhL[0], hH, ghr); ghz = mfma16(WhL[1], hH, ghz); ghn = mfma16(WhL[2], hH, ghn); \
  ghr = mfma16(WhH[0], hL, ghr); ghz = mfma16(WhH[1], hL, ghz); ghn = mfma16(WhH[2], hL, ghn); \
  u32 np0=0, np1=0; \
  short4v hHn = {0,0,0,0}, hLn = {0,0,0,0}; \
  _Pragma("unroll") \
  for (int rg=0; rg<4; ++rg){ \
    float Ct = 0.f; \
    if (PASS>=2){ u32 wb = (rg<2)? NV1.x : NV1.y; Ct = bf2f((u16)(wb >> ((rg&1)*16))) * rv1[rg]; } \
    if (PASS==3){ u32 wb = (rg<2)? NV2.x : NV2.y; Ct += bf2f((u16)(wb >> ((rg&1)*16))) * rv2[rg]; } \
    float rr = fsig(giA0[rg] + ghr[rg]); \
    float zz = fsig(giA1[rg] + ghz[rg] + Ct); \
    float nn = ftanh(giA2[rg] + rr*ghn[rg]); \
    float hvv = nn + zz*(hprev[rg]-nn); \
    hprev[rg] = hvv; \
    if (PASS<=2){ \
      u32 nb = f2bf(nn); \
      if (rg==0) np0 |= nb; else if (rg==1) np0 |= nb<<16; else if (rg==2) np1 |= nb; else np1 |= nb<<16; \
    } \
    u16 hb = f2bf(hvv); \
    hHn[rg] = (short)hb; \
    hLn[rg] = (short)f2bf(hvv - bf2f(hb)); \
  } \
  if (PASS<=2){ uint2 stv; stv.x=np0; stv.y=np1; *(uint2*)(Nw + nbase + (size_t)(tt)*2048) = stv; } \
  hH = hHn; hL = hLn; \
}

  LOADA(0);
  for (int t=0; t<48; t+=2){
    LOADB(t+1);
    GRU_STEP(t,   A0,A1,A2,A3, AN1,AN2);
    LOADA(t+2);
    GRU_STEP(t+1, Bb0,Bb1,Bb2,Bb3, BN1,BN2);
  }
  LOADB(49);
  GRU_STEP(48, A0,A1,A2,A3, AN1,AN2);
  GRU_STEP(49, Bb0,Bb1,Bb2,Bb3, BN1,BN2);
#undef GRU_STEP
#undef LOADA
#undef LOADB

  float4 stv; stv.x=hprev[0]; stv.y=hprev[1]; stv.z=hprev[2]; stv.w=hprev[3];
  *(float4*)(behE + (((size_t)b*64 + k)*4 + m)*16 + j0) = stv;
}

// ---------------- softmax(b)+v+v_ (parallel softmax, 4 threads/row); vBp written directly ----------------
__global__ __launch_bounds__(256) void k_cv(const float* __restrict__ bmat, const float* __restrict__ behE,
  const float* __restrict__ W, const float* __restrict__ alpha, const float* __restrict__ wv,
  const float* __restrict__ bias, float* __restrict__ vout, u32* __restrict__ vBp)
{
  __shared__ float cm[64][65];
  __shared__ float vsh[64][17];
  __shared__ float besh[4096];
  __shared__ float smx[4][64], ssm[4][64];
  int b = blockIdx.x, tid = threadIdx.x;
  for (int it=0; it<16; ++it){
    int li = tid + it*256;
    cm[li>>6][li&63] = bmat[(size_t)b*4096 + li];
    besh[li] = behE[(size_t)b*4096 + li];
  }
  __syncthreads();
  {
    int row = tid & 63, sl = tid >> 6;
    int c0 = sl*16;
    float mx = -1e30f;
    #pragma unroll
    for (int c=0;c<16;c++) mx = fmaxf(mx, cm[row][c0+c]);
    smx[sl][row] = mx;
    __syncthreads();
    float m4 = fmaxf(fmaxf(smx[0][row],smx[1][row]), fmaxf(smx[2][row],smx[3][row]));
    float sm = 0.f;
    #pragma unroll
    for (int c=0;c<16;c++){ float e = fexp(cm[row][c0+c]-m4); cm[row][c0+c]=e; sm+=e; }
    ssm[sl][row] = sm;
    __syncthreads();
    float inv = 1.0f/(ssm[0][row]+ssm[1][row]+ssm[2][row]+ssm[3][row]);
    #pragma unroll
    for (int c=0;c<16;c++) cm[row][c0+c] *= inv;
  }
  __syncthreads();
  int j = tid & 63, dq = tid>>6;
  float a0=0,a1=0,a2=0,a3=0;
  for (int i=0;i<64;++i){
    float cij = cm[i][j];
    #pragma unroll
    for (int q=0;q<4;++q){
      int d = dq*4+q;
      const float* wp = W + ((size_t)((i*16+d)*4))*64 + j;
      float uu = besh[i*64+d]*wp[0] + besh[i*64+16+d]*wp[64]
               + besh[i*64+32+d]*wp[128] + besh[i*64+48+d]*wp[192];
      float cu = cij*uu;
      if (q==0) a0 += cu; else if (q==1) a1 += cu; else if (q==2) a2 += cu; else a3 += cu;
    }
  }
  float al = alpha[0];
  a0*=al; a1*=al; a2*=al; a3*=al;
  vsh[j][dq*4]=a0; vsh[j][dq*4+1]=a1; vsh[j][dq*4+2]=a2; vsh[j][dq*4+3]=a3;
  float* vp = vout + ((size_t)b*64 + j)*16 + dq*4;
  vp[0]=a0; vp[1]=a1; vp[2]=a2; vp[3]=a3;
  __syncthreads();
  if (tid < 64){
    float s=0.f;
    #pragma unroll
    for (int dd=0; dd<16; ++dd){ float q = vsh[tid][dd]; s += q*q; }
    float val = sqrtf(s)*wv[tid] + bias[tid];
    u16 h = f2bf(val); u16 l = f2bf(val - bf2f(h));
    vBp[b*64 + tid] = (u32)h | ((u32)l<<16);
  }
}

// ---------------- fused logits+exp+p via MFMA (split-bf16), T14 prefetch, private partials ----------------
__global__ __launch_bounds__(256) void k_pfused(const u32* __restrict__ vBp, const float* __restrict__ E,
  float* __restrict__ partial)
{
  __shared__ u16 etAh[32*72], etAl[32*72];     // [item][c] pad 72
  __shared__ u16 etBh[64*32], etBl[64*32];     // [c/d][item]
  __shared__ u32 exT[128*36];                  // [b][item] packed h|l, pad 36
  int tid = threadIdx.x, lane = tid&63, w = tid>>6;
  int n16 = lane&15, quad = lane>>4;

  // preload v B-fragments (constant over items)
  short8 vh[2][2], vl[2][2];
  #pragma unroll
  for (int nt2=0; nt2<2; ++nt2){
    int b = (2*w+nt2)*16 + n16;
    #pragma unroll
    for (int s=0; s<2; ++s){
      u32 tmp[8];
      const u32* src = vBp + b*64 + s*32 + quad*8;
      #pragma unroll
      for (int q=0;q<8;q++) tmp[q]=src[q];
      unpack8(tmp, vh[nt2][s], vl[nt2][s]);
    }
  }
  f32x4 pacc[2][4];
  #pragma unroll
  for (int a2=0;a2<2;a2++)
    #pragma unroll
    for (int b2=0;b2<4;b2++){ pacc[a2][b2][0]=0.f; pacc[a2][b2][1]=0.f; pacc[a2][b2][2]=0.f; pacc[a2][b2][3]=0.f; }
  float srun[2] = {0.f, 0.f};

  int start = blockIdx.x*CHUNK3;
  int bend = start + CHUNK3; if (bend > NIT) bend = NIT;
  int sitem = tid>>3, sc0 = (tid&7)*8;

  // prologue: load chunk 0's E slice into registers
  float vals[8]; float mk;
  {
    int gidx = start + sitem;
    int ga = (gidx < NIT) ? gidx : 0;
    mk = (gidx < NIT) ? 1.f : 0.f;
    float4 a = ((const float4*)E)[(size_t)ga*16 + (sc0>>2)];
    float4 b2 = ((const float4*)E)[(size_t)ga*16 + (sc0>>2) + 1];
    vals[0]=a.x; vals[1]=a.y; vals[2]=a.z; vals[3]=a.w;
    vals[4]=b2.x; vals[5]=b2.y; vals[6]=b2.z; vals[7]=b2.w;
  }
  for (int ch=0; ch<NCH3; ++ch){
    int i0 = start + ch*32;
    if (i0 >= bend) break;
    // ---- stage current 32-item tile from registers ----
    {
      u16 hh[8], ll[8];
      #pragma unroll
      for (int q=0;q<8;q++){ float vq = vals[q]*mk; hh[q]=f2bf(vq); ll[q]=f2bf(vq-bf2f(hh[q])); }
      *(short8*)(etAh + sitem*72 + sc0) = *(short8*)hh;
      *(short8*)(etAl + sitem*72 + sc0) = *(short8*)ll;
      #pragma unroll
      for (int q=0;q<8;q++){
        etBh[(sc0+q)*32 + sitem] = hh[q];
        etBl[(sc0+q)*32 + sitem] = ll[q];
      }
    }
    __syncthreads();
    // ---- issue next tile's loads (in flight across GEMM1+GEMM2) ----
    {
      int gidx = i0 + 32 + sitem;
      int ga = (gidx < NIT) ? gidx : 0;
      mk = (gidx < NIT) ? 1.f : 0.f;
      float4 a = ((const float4*)E)[(size_t)ga*16 + (sc0>>2)];
      float4 b2 = ((const float4*)E)[(size_t)ga*16 + (sc0>>2) + 1];
      vals[0]=a.x; vals[1]=a.y; vals[2]=a.z; vals[3]=a.w;
      vals[4]=b2.x; vals[5]=b2.y; vals[6]=b2.z; vals[7]=b2.w;
    }
    // ---- GEMM1: logits[item][b], exp, write exT ----
    short8 Eh[2][2], El[2][2];
    #pragma unroll
    for (int mt=0; mt<2; ++mt)
      #pragma unroll
      for (int s=0; s<2; ++s){
        Eh[mt][s] = *(const short8*)(etAh + (mt*16 + n16)*72 + s*32 + quad*8);
        El[mt][s] = *(const short8*)(etAl + (mt*16 + n16)*72 + s*32 + quad*8);
      }
    #pragma unroll
    for (int mt=0; mt<2; ++mt){
      #pragma unroll
      for (int nt2=0; nt2<2; ++nt2){
        f32x4 a = {0.f,0.f,0.f,0.f};
        #pragma unroll
        for (int s=0; s<2; ++s){
          a = __builtin_amdgcn_mfma_f32_16x16x32_bf16(Eh[mt][s], vh[nt2][s], a, 0,0,0);
          a = __builtin_amdgcn_mfma_f32_16x16x32_bf16(Eh[mt][s], vl[nt2][s], a, 0,0,0);
          a = __builtin_amdgcn_mfma_f32_16x16x32_bf16(El[mt][s], vh[nt2][s], a, 0,0,0);
        }
        u32 packed[4];
        #pragma unroll
        for (int rg=0; rg<4; ++rg){
          int it_g = i0 + mt*16 + quad*4 + rg;
          float ex = (it_g < bend)? fexp(a[rg]) : 0.f;
          srun[nt2] += ex;
          u16 h = f2bf(ex); u16 l = f2bf(ex - bf2f(h));
          packed[rg] = (u32)h | ((u32)l<<16);
        }
        int bl = (2*w+nt2)*16 + n16;
        uint4 st; st.x=packed[0]; st.y=packed[1]; st.z=packed[2]; st.w=packed[3];
        *(uint4*)(exT + bl*36 + mt*16 + quad*4) = st;
      }
    }
    __syncthreads();
    // ---- GEMM2: p[b][d] += exp @ E ----
    short8 Xh[2], Xl[2];
    #pragma unroll
    for (int mt2=0; mt2<2; ++mt2){
      int bl = (2*w+mt2)*16 + n16;
      uint4 t0 = *(const uint4*)(exT + bl*36 + quad*8);
      uint4 t1 = *(const uint4*)(exT + bl*36 + quad*8 + 4);
      u32 tmp[8] = {t0.x,t0.y,t0.z,t0.w,t1.x,t1.y,t1.z,t1.w};
      unpack8(tmp, Xh[mt2], Xl[mt2]);
    }
    #pragma unroll
    for (int nt3=0; nt3<4; ++nt3){
      int d = nt3*16 + n16;
      short8 Bh = *(const short8*)(etBh + d*32 + quad*8);
      short8 Bl = *(const short8*)(etBl + d*32 + quad*8);
      #pragma unroll
      for (int mt2=0; mt2<2; ++mt2){
        pacc[mt2][nt3] = __builtin_amdgcn_mfma_f32_16x16x32_bf16(Xh[mt2], Bh, pacc[mt2][nt3], 0,0,0);
        pacc[mt2][nt3] = __builtin_amdgcn_mfma_f32_16x16x32_bf16(Xh[mt2], Bl, pacc[mt2][nt3], 0,0,0);
        pacc[mt2][nt3] = __builtin_amdgcn_mfma_f32_16x16x32_bf16(Xl[mt2], Bh, pacc[mt2][nt3], 0,0,0);
      }
    }
    __syncthreads();
  }
  // ---- epilogue: private partial slice ----
  float* dst = partial + (size_t)blockIdx.x*PSTRIDE;
  #pragma unroll
  for (int mt2=0; mt2<2; ++mt2)
    #pragma unroll
    for (int nt3=0; nt3<4; ++nt3)
      #pragma unroll
      for (int rg=0; rg<4; ++rg){
        int b_g = (2*w+mt2)*16 + quad*4 + rg;
        int d_g = nt3*16 + n16;
        dst[b_g*64 + d_g] = pacc[mt2][nt3][rg];
      }
  #pragma unroll
  for (int nt2=0; nt2<2; ++nt2){
    float vsum = srun[nt2];
    vsum += __shfl_xor(vsum, 16);
    vsum += __shfl_xor(vsum, 32);
    if (quad == 0) dst[8192 + (2*w+nt2)*16 + n16] = vsum;
  }
}

// ---------------- fused combine + r: p in LDS, r[b][j][l] = sum_d cat(p,v)*Wc ----------------
__global__ __launch_bounds__(256) void k_pcr(const float* __restrict__ partial,
  const float* __restrict__ v, const float* __restrict__ Wc,
  float* __restrict__ r, float* __restrict__ rT)
{
  __shared__ float ared[4][64];
  __shared__ float sred[256];
  __shared__ float psh[64];
  int b = blockIdx.x, tid = threadIdx.x;   // 128 blocks, one per b
  int d = tid & 63, qs = tid >> 6;
  float a = 0.f;
  for (int q = qs; q < NBP3; q += 4)
    a += partial[(size_t)q*PSTRIDE + b*64 + d];
  ared[qs][d] = a;
  sred[tid] = partial[(size_t)tid*PSTRIDE + 8192 + b]
            + partial[(size_t)(tid+256)*PSTRIDE + 8192 + b];
  __syncthreads();
  if (tid < 64){
    float sv = sred[tid] + sred[tid+64] + sred[tid+128] + sred[tid+192];
    sv += __shfl_xor(sv, 1);  sv += __shfl_xor(sv, 2);  sv += __shfl_xor(sv, 4);
    sv += __shfl_xor(sv, 8);  sv += __shfl_xor(sv, 16); sv += __shfl_xor(sv, 32);
    float at = ared[0][tid]+ared[1][tid]+ared[2][tid]+ared[3][tid];
    psh[tid] = at / sv;
  }
  __syncthreads();
  int l = tid & 15, jbase = tid >> 4;      // 16 j's per pass, 4 passes
  #pragma unroll
  for (int jb=0; jb<4; ++jb){
    int j = jb*16 + jbase;
    const float* wc = Wc + ((size_t)j*80)*16 + l;
    float acc = 0.f;
    #pragma unroll 8
    for (int dd=0; dd<64; ++dd) acc += psh[dd]*wc[dd*16];
    const float* vb = v + ((size_t)b*64 + j)*16;
    #pragma unroll
    for (int dd=0; dd<16; ++dd) acc += vb[dd]*wc[(64+dd)*16];
    r[((size_t)b*64+j)*16 + l] = acc;
    rT[((size_t)b*16+l)*64 + j] = acc;
  }
}

// ---------------- b[b][i][j] += sum_d u[b][i][d][j]*r[b][j][d], u recomputed ----------------
__global__ __launch_bounds__(256) void k_bupd(const float* __restrict__ behE, const float* __restrict__ W,
  const float* __restrict__ rT, float* __restrict__ bmat)
{
  int lane = threadIdx.x & 63;
  int idx = blockIdx.x*4 + (threadIdx.x>>6);
  int b = idx >> 6, i = idx & 63;
  const float* be = behE + (size_t)idx*64;
  const float* rp = rT + (size_t)b*1024;
  float acc = 0.f;
  #pragma unroll
  for (int d=0; d<16; ++d){
    const float* wp = W + ((size_t)((i*16+d)*4))*64 + lane;
    float uu = be[d]*wp[0] + be[16+d]*wp[64] + be[32+d]*wp[128] + be[48+d]*wp[192];
    acc += uu * rp[d*64 + lane];
  }
  bmat[(size_t)idx*64 + lane] += acc;
}

// ---------------- final logits via MFMA (split-bf16), coalesced out[b][i] ----------------
__global__ __launch_bounds__(256) void k_logits(const u32* __restrict__ vBp, const float* __restrict__ E,
  float* __restrict__ out)
{
  __shared__ u16 etAh[64*72], etAl[64*72];   // [item][c] pad 72
  __shared__ float lt[128*68];               // [b][item] pad 68
  int tid = threadIdx.x, lane = tid&63, w = tid>>6;
  int n16 = lane&15, quad = lane>>4;
  // preload v B-fragments
  short8 vh[2][2], vl[2][2];
  #pragma unroll
  for (int nt2=0; nt2<2; ++nt2){
    int b = (2*w+nt2)*16 + n16;
    #pragma unroll
    for (int s=0; s<2; ++s){
      u32 tmp[8];
      const u32* src = vBp + b*64 + s*32 + quad*8;
      #pragma unroll
      for (int q=0;q<8;q++) tmp[q]=src[q];
      unpack8(tmp, vh[nt2][s], vl[nt2][s]);
    }
  }
  int i0 = blockIdx.x*64;
  // stage 64 items
  {
    int sitem = tid>>2, sc0 = (tid&3)*16;
    int gidx = i0 + sitem;
    float vals[16];
    if (gidx < NIT){
      #pragma unroll
      for (int q=0;q<4;q++){
        float4 a = ((const float4*)E)[(size_t)gidx*16 + (sc0>>2) + q];
        vals[4*q]=a.x; vals[4*q+1]=a.y; vals[4*q+2]=a.z; vals[4*q+3]=a.w;
      }
    } else {
      #pragma unroll
      for (int q=0;q<16;q++) vals[q]=0.f;
    }
    u16 hh[16], ll[16];
    #pragma unroll
    for (int q=0;q<16;q++){ hh[q]=f2bf(vals[q]); ll[q]=f2bf(vals[q]-bf2f(hh[q])); }
    *(short8*)(etAh + sitem*72 + sc0)     = *(short8*)hh;
    *(short8*)(etAh + sitem*72 + sc0 + 8) = *(short8*)(hh+8);
    *(short8*)(etAl + sitem*72 + sc0)     = *(short8*)ll;
    *(short8*)(etAl + sitem*72 + sc0 + 8) = *(short8*)(ll+8);
  }
  __syncthreads();
  #pragma unroll
  for (int mt=0; mt<4; ++mt){
    short8 Eh[2], El[2];
    #pragma unroll
    for (int s=0; s<2; ++s){
      Eh[s] = *(const short8*)(etAh + (mt*16 + n16)*72 + s*32 + quad*8);
      El[s] = *(const short8*)(etAl + (mt*16 + n16)*72 + s*32 + quad*8);
    }
    #pragma unroll
    for (int nt2=0; nt2<2; ++nt2){
      f32x4 a = {0.f,0.f,0.f,0.f};
      #pragma unroll
      for (int s=0; s<2; ++s){
        a = __builtin_amdgcn_mfma_f32_16x16x32_bf16(Eh[s], vh[nt2][s], a, 0,0,0);
        a = __builtin_amdgcn_mfma_f32_16x16x32_bf16(Eh[s], vl[nt2][s], a, 0,0,0);
        a = __builtin_amdgcn_mfma_f32_16x16x32_bf16(El[s], vh[nt2][s], a, 0,0,0);
      }
      int b = (2*w+nt2)*16 + n16;
      *(float4*)(lt + b*68 + mt*16 + quad*4) = *(float4*)&a;
    }
  }
  __syncthreads();
  int col = tid & 63, rgp = tid >> 6;
  if (i0 + col < NIT){
    #pragma unroll
    for (int rr=0; rr<32; ++rr){
      int b = rgp*32 + rr;
      out[(size_t)b*NIT + i0 + col] = lt[b*68 + col];
    }
  }
}

extern "C" void kernel_launch(void* const* d_in, const int* in_sizes, int n_in,
                              void* d_out, int out_size, void* d_ws, size_t ws_size,
                              hipStream_t stream)
{
  (void)in_sizes; (void)n_in; (void)out_size; (void)ws_size;
  const int*   s0 = (const int*)d_in[0];
  const int*   s1 = (const int*)d_in[1];
  const int*   s2 = (const int*)d_in[2];
  const int*   s3 = (const int*)d_in[3];
  const float* E  = (const float*)d_in[4];
  const float* W  = (const float*)d_in[5];
  const float* Wc = (const float*)d_in[6];
  const float* alpha = (const float*)d_in[7];
  const float* wv    = (const float*)d_in[8];
  const float* bias  = (const float*)d_in[9];
  const float* Wx = (const float*)d_in[10];
  const float* bx = (const float*)d_in[11];
  const float* Wh = (const float*)d_in[12];
  const float* bh = (const float*)d_in[13];

  char* ws = (char*)d_ws;
  size_t off = 0;
  auto alloc = [&](size_t bytes)->void*{ void* q = ws + off; off += (bytes + 255) & ~(size_t)255; return q; };
  u16*   N1   = (u16*)  alloc((size_t)M_*K_*T_*B_*16*2);   // 52.4 MB
  u16*   N2   = (u16*)  alloc((size_t)M_*K_*T_*B_*16*2);   // 52.4 MB
  u16*   xh   = (u16*)  alloc((size_t)M_*6400*64*2);
  u16*   xl   = (u16*)  alloc((size_t)M_*6400*64*2);
  u16*   wh   = (u16*)  alloc((size_t)M_*3072*64*2);
  u16*   wl   = (u16*)  alloc((size_t)M_*3072*64*2);
  float* bmat = (float*)alloc((size_t)B_*64*64*4);
  float* behE = (float*)alloc((size_t)B_*64*4*16*4);
  float* v    = (float*)alloc((size_t)B_*64*16*4);
  u32*   vBp  = (u32*)  alloc((size_t)128*64*4);
  float* r1   = (float*)alloc((size_t)B_*64*16*4);
  float* rT1  = (float*)alloc((size_t)B_*64*16*4);
  float* r2   = (float*)alloc((size_t)B_*64*16*4);
  float* rT2  = (float*)alloc((size_t)B_*64*16*4);
  float* partial = (float*)alloc((size_t)NBP3*PSTRIDE*4); // 17 MB
  // total ~140 MB

  hipMemsetAsync(bmat, 0, (size_t)B_*64*64*4, stream);
  k_prep_x<<<800,256,0,stream>>>(s0,s1,s2,s3,E,xh,xl);
  k_prep_w<<<192,256,0,stream>>>(Wx,wh,wl);

  // ---- routing iteration 1: C=0, write N1 ----
  k_gru_mfma<1><<<512,256,0,stream>>>(xh,xl,wh,wl,Wh,bx,bh,
                                      nullptr,nullptr,nullptr,nullptr, N1, behE);
  k_cv<<<128,256,0,stream>>>(bmat,behE,W,alpha,wv,bias,v,vBp);
  k_pfused<<<NBP3,256,0,stream>>>(vBp,E,partial);
  k_pcr<<<128,256,0,stream>>>(partial,v,Wc,r1,rT1);
  k_bupd<<<2048,256,0,stream>>>(behE,W,rT1,bmat);

  // ---- routing iteration 2: C = N1*r1, write N2 ----
  k_gru_mfma<2><<<512,256,0,stream>>>(xh,xl,wh,wl,Wh,bx,bh,
                                      r1,nullptr, N1,nullptr, N2, behE);
  k_cv<<<128,256,0,stream>>>(bmat,behE,W,alpha,wv,bias,v,vBp);
  k_pfused<<<NBP3,256,0,stream>>>(vBp,E,partial);
  k_pcr<<<128,256,0,stream>>>(partial,v,Wc,r2,rT2);
  k_bupd<<<2048,256,0,stream>>>(behE,W,rT2,bmat);

  // ---- final pass: C = N1*r1 + N2*r2 ----
  k_gru_mfma<3><<<512,256,0,stream>>>(xh,xl,wh,wl,Wh,bx,bh,
                                      r1,r2, N1,N2, nullptr, behE);
  k_cv<<<128,256,0,stream>>>(bmat,behE,W,alpha,wv,bias,v,vBp);
  k_logits<<<1563,256,0,stream>>>(vBp,E,(float*)d_out);
}

// Round 10
// 472.008 us; speedup vs baseline: 1.0873x; 1.0873x over previous
//
#include <hip/hip_runtime.h>
#include <hip/hip_bf16.h>
#include <cstdint>
#include <cstddef>

#define B_   128
#define T_   50
#define M_   4
#define D_   64
#define K_   64
#define L_   16
#define NIT  100001
#define NBP3 512
#define CHUNK3 196     /* 512*196 = 100352 >= NIT */
#define NCH3 7         /* ceil(196/32) */
#define PSTRIDE 8320   /* 8192 p-words + 128 srun words per block slice */

typedef unsigned short u16;
typedef unsigned int   u32;
typedef __attribute__((ext_vector_type(8))) short short8;
typedef __attribute__((ext_vector_type(4))) short short4v;
typedef __attribute__((ext_vector_type(4))) float f32x4;

__device__ __forceinline__ float bf2f(u16 v){ u32 u = ((u32)v)<<16; float f; __builtin_memcpy(&f,&u,4); return f; }
__device__ __forceinline__ u16 f2bf(float f){
  u32 u; __builtin_memcpy(&u,&f,4);
  u32 r = (u + 0x7FFFu + ((u>>16)&1u)) >> 16;
  return (u16)r;
}
__device__ __forceinline__ float fexp(float x){ return __builtin_amdgcn_exp2f(x*1.4426950408889634f); }
__device__ __forceinline__ float fsig(float x){ return __builtin_amdgcn_rcpf(1.0f + fexp(-x)); }
__device__ __forceinline__ float ftanh(float x){ return 1.0f - 2.0f*__builtin_amdgcn_rcpf(1.0f + fexp(2.0f*x)); }
__device__ __forceinline__ void unpack8(const u32* s, short8& h, short8& l){
  #pragma unroll
  for (int q=0;q<8;q++){ h[q]=(short)(s[q]&0xFFFFu); l[q]=(short)(s[q]>>16); }
}

#define MFMA32(A,Bv,C) __builtin_amdgcn_mfma_f32_16x16x32_bf16(A,Bv,C,0,0,0)

#if __has_builtin(__builtin_amdgcn_mfma_f32_16x16x16bf16_1k)
__device__ __forceinline__ f32x4 mfma16(short4v a, short4v b, f32x4 c){
  return __builtin_amdgcn_mfma_f32_16x16x16bf16_1k(a,b,c,0,0,0);
}
#elif __has_builtin(__builtin_amdgcn_mfma_f32_16x16x16_bf16)
__device__ __forceinline__ f32x4 mfma16(short4v a, short4v b, f32x4 c){
  return __builtin_amdgcn_mfma_f32_16x16x16_bf16(a,b,c,0,0,0);
}
#else
__device__ __forceinline__ f32x4 mfma16(short4v a, short4v b, f32x4 c){
  asm("v_mfma_f32_16x16x16_bf16 %0, %1, %2, %0" : "+v"(c) : "v"(a), "v"(b));
  return c;
}
#endif

// ---------------- prep x: embed+mask, split fp32 -> bf16 hi/lo, layout [m][t*128+b][64] ----------------
__global__ __launch_bounds__(256) void k_prep_x(const int* __restrict__ s0, const int* __restrict__ s1,
  const int* __restrict__ s2, const int* __restrict__ s3, const float* __restrict__ E,
  u16* __restrict__ xh, u16* __restrict__ xl)
{
  int id = blockIdx.x*256 + threadIdx.x;
  int e8 = id & 7;
  int rm = id >> 3;
  int m = rm / 6400; int r = rm - m*6400;
  int t = r >> 7, b = r & 127;
  const int* sq = (m==0)? s0 : (m==1)? s1 : (m==2)? s2 : s3;
  int idx = sq[b*T_ + t];
  float sc = (idx==0)? 0.0f : 1.0f;
  const float4* ep = (const float4*)(E + (size_t)idx*64 + e8*8);
  float4 v0 = ep[0], v1 = ep[1];
  float vals[8] = {v0.x,v0.y,v0.z,v0.w,v1.x,v1.y,v1.z,v1.w};
  u32 hw[4], lw[4];
  #pragma unroll
  for (int q=0;q<4;q++){
    float f0 = vals[2*q]*sc, f1 = vals[2*q+1]*sc;
    u16 h0 = f2bf(f0), h1 = f2bf(f1);
    u16 l0 = f2bf(f0 - bf2f(h0)), l1 = f2bf(f1 - bf2f(h1));
    hw[q] = (u32)h0 | ((u32)h1<<16);
    lw[q] = (u32)l0 | ((u32)l1<<16);
  }
  size_t off = (size_t)rm*64 + e8*8;
  uint4 hv; hv.x=hw[0]; hv.y=hw[1]; hv.z=hw[2]; hv.w=hw[3];
  uint4 lv; lv.x=lw[0]; lv.y=lw[1]; lv.z=lw[2]; lv.w=lw[3];
  *(uint4*)(xh + off) = hv;
  *(uint4*)(xl + off) = lv;
}

// ---------------- prep W: transpose Wx[m][d][g] -> [m][g][d], split bf16 hi/lo ----------------
__global__ __launch_bounds__(256) void k_prep_w(const float* __restrict__ Wx,
  u16* __restrict__ wh, u16* __restrict__ wl)
{
  __shared__ float tl[64][65];
  int m = blockIdx.x / 48, gt = blockIdx.x % 48;
  for (int it=0; it<16; ++it){
    int li = threadIdx.x + it*256;
    int dl = li >> 6, gl = li & 63;
    tl[dl][gl] = Wx[((size_t)m*64 + dl)*3072 + gt*64 + gl];
  }
  __syncthreads();
  for (int it=0; it<2; ++it){
    int unit = threadIdx.x + it*256;
    int gl = unit >> 3, d8 = unit & 7;
    u32 hw[4], lw[4];
    #pragma unroll
    for (int q=0;q<4;q++){
      float f0 = tl[d8*8+2*q][gl], f1 = tl[d8*8+2*q+1][gl];
      u16 h0 = f2bf(f0), h1 = f2bf(f1);
      u16 l0 = f2bf(f0 - bf2f(h0)), l1 = f2bf(f1 - bf2f(h1));
      hw[q] = (u32)h0 | ((u32)h1<<16);
      lw[q] = (u32)l0 | ((u32)l1<<16);
    }
    size_t off = ((size_t)m*3072 + gt*64 + gl)*64 + d8*8;
    uint4 hv; hv.x=hw[0]; hv.y=hw[1]; hv.z=hw[2]; hv.w=hw[3];
    uint4 lv; lv.x=lw[0]; lv.y=lw[1]; lv.z=lw[2]; lv.w=lw[3];
    *(uint4*)(wh + off) = hv;
    *(uint4*)(wl + off) = lv;
  }
}

// ---------------- fused GRU (round-4 proven, FROZEN): unroll-2 A/B pipeline, scalar f2bf packing ----------------
// PASS=1: C=0, write N1.  PASS=2: C=N1*r1, write N2.  PASS=3: C=N1*r1+N2*r2, no N write.
template<int PASS>
__global__ __launch_bounds__(256,2) void k_gru_mfma(
  const u16* __restrict__ xh, const u16* __restrict__ xl,
  const u16* __restrict__ wh, const u16* __restrict__ wl,
  const float* __restrict__ Wh, const float* __restrict__ bx, const float* __restrict__ bhp,
  const float* __restrict__ rp1, const float* __restrict__ rp2,
  const u16* __restrict__ Nr1, const u16* __restrict__ Nr2,
  u16* __restrict__ Nw, float* __restrict__ behE)
{
  int tid = threadIdx.x;
  int lane = tid & 63;
  int n16 = lane & 15, quad = lane >> 4;
  int j0 = quad*4;
  int wid = blockIdx.x*4 + (tid>>6);          // [0,2048)
  int bt = wid & 7, k = (wid>>3)&63, m = wid>>9;
  int b = bt*16 + n16;

  // Wx A-fragments (rows g = gate*1024 + k*16 + [0,16))
  short8 WxH[3][2], WxL[3][2];
  #pragma unroll
  for (int g=0; g<3; ++g){
    int grow = g*1024 + k*16 + n16;
    #pragma unroll
    for (int c=0; c<2; ++c){
      size_t off = ((size_t)(m*3072 + grow))*64 + c*32 + quad*8;
      WxH[g][c] = *(const short8*)(wh + off);
      WxL[g][c] = *(const short8*)(wl + off);
    }
  }
  // Wh A-fragments, split bf16: A[m=n16][k=quad*4+i] = Wh[l=quad*4+i][g*16+n16]
  const float* whp = Wh + ((size_t)(m*64+k)*16)*48;
  short4v WhH[3], WhL[3];
  #pragma unroll
  for (int g=0; g<3; ++g){
    short4v hhv, llv;
    #pragma unroll
    for (int i=0;i<4;i++){
      float w = whp[(j0+i)*48 + g*16 + n16];
      u16 hbits = f2bf(w);
      hhv[i] = (short)hbits;
      llv[i] = (short)f2bf(w - bf2f(hbits));
    }
    WhH[g]=hhv; WhL[g]=llv;
  }
  // biases: r,z fold bh into gi acc init; n keeps bh_n in gh acc init
  float biasv[3][4], bhn[4];
  #pragma unroll
  for (int g=0; g<3; ++g)
    #pragma unroll
    for (int rg=0; rg<4; ++rg){
      int j = j0+rg;
      float tb = bx[m*3072 + g*1024 + k*16 + j];
      if (g<2) tb += bhp[(m*64+k)*48 + g*16 + j];
      biasv[g][rg] = tb;
    }
  #pragma unroll
  for (int rg=0; rg<4; ++rg) bhn[rg] = bhp[(m*64+k)*48 + 32 + j0 + rg];

  float rv1[4]={0.f,0.f,0.f,0.f}, rv2[4]={0.f,0.f,0.f,0.f};
  if (PASS>=2){
    float4 q = *(const float4*)(rp1 + ((size_t)b*64+k)*16 + j0);
    rv1[0]=q.x; rv1[1]=q.y; rv1[2]=q.z; rv1[3]=q.w;
  }
  if (PASS==3){
    float4 q = *(const float4*)(rp2 + ((size_t)b*64+k)*16 + j0);
    rv2[0]=q.x; rv2[1]=q.y; rv2[2]=q.z; rv2[3]=q.w;
  }

  size_t xrow  = ((size_t)m*6400 + bt*16 + n16)*64 + quad*8;
  size_t nbase = ((size_t)(m*64+k))*102400 + (size_t)b*16 + j0;

  short4v hH = {0,0,0,0}, hL = {0,0,0,0};
  float hprev[4] = {0.f,0.f,0.f,0.f};

  // double-buffer registers
  short8 A0,A1,A2,A3, Bb0,Bb1,Bb2,Bb3;
  uint2 AN1={0,0}, AN2={0,0}, BN1={0,0}, BN2={0,0};

#define LOADA(tt) { size_t xo = xrow + (size_t)(tt)*8192; \
  A0 = *(const short8*)(xh + xo); A1 = *(const short8*)(xh + xo + 32); \
  A2 = *(const short8*)(xl + xo); A3 = *(const short8*)(xl + xo + 32); \
  if (PASS>=2) AN1 = *(const uint2*)(Nr1 + nbase + (size_t)(tt)*2048); \
  if (PASS==3) AN2 = *(const uint2*)(Nr2 + nbase + (size_t)(tt)*2048); }
#define LOADB(tt) { size_t xo = xrow + (size_t)(tt)*8192; \
  Bb0 = *(const short8*)(xh + xo); Bb1 = *(const short8*)(xh + xo + 32); \
  Bb2 = *(const short8*)(xl + xo); Bb3 = *(const short8*)(xl + xo + 32); \
  if (PASS>=2) BN1 = *(const uint2*)(Nr1 + nbase + (size_t)(tt)*2048); \
  if (PASS==3) BN2 = *(const uint2*)(Nr2 + nbase + (size_t)(tt)*2048); }

#define GRU_STEP(tt, X0,X1,X2,X3, NV1, NV2) { \
  f32x4 giA0 = {biasv[0][0], biasv[0][1], biasv[0][2], biasv[0][3]}; \
  f32x4 giA1 = {biasv[1][0], biasv[1][1], biasv[1][2], biasv[1][3]}; \
  f32x4 giA2 = {biasv[2][0], biasv[2][1], biasv[2][2], biasv[2][3]}; \
  giA0 = MFMA32(WxH[0][0], X0, giA0); giA1 = MFMA32(WxH[1][0], X0, giA1); giA2 = MFMA32(WxH[2][0], X0, giA2); \
  giA0 = MFMA32(WxH[0][1], X1, giA0); giA1 = MFMA32(WxH[1][1], X1, giA1); giA2 = MFMA32(WxH[2][1], X1, giA2); \
  giA0 = MFMA32(WxL[0][0], X0, giA0); giA1 = MFMA32(WxL[1][0], X0, giA1); giA2 = MFMA32(WxL[2][0], X0, giA2); \
  giA0 = MFMA32(WxL[0][1], X1, giA0); giA1 = MFMA32(WxL[1][1], X1, giA1); giA2 = MFMA32(WxL[2][1], X1, giA2); \
  giA0 = MFMA32(WxH[0][0], X2, giA0); giA1 = MFMA32(WxH[1][0], X2, giA1); giA2 = MFMA32(WxH[2][0], X2, giA2); \
  giA0 = MFMA32(WxH[0][1], X3, giA0); giA1 = MFMA32(WxH[1][1], X3, giA1); giA2 = MFMA32(WxH[2][1], X3, giA2); \
  f32x4 ghr = {0.f,0.f,0.f,0.f}, ghz = {0.f,0.f,0.f,0.f}; \
  f32x4 ghn = {bhn[0], bhn[1], bhn[2], bhn[3]}; \
  ghr = mfma16(WhH[0], hH, ghr); ghz = mfma16(WhH[1], hH, ghz); ghn = mfma16(WhH[2], hH, ghn); \
  ghr = mfma16(WhL[0], hH, ghr); ghz = mfma16(WhL[1], hH, ghz); ghn = mfma16(WhL[2], hH, ghn); \
  ghr = mfma16(WhH[0], hL, ghr); ghz = mfma16(WhH[1], hL, ghz); ghn = mfma16(WhH[2], hL, ghn); \
  u32 np0=0, np1=0; \
  short4v hHn = {0,0,0,0}, hLn = {0,0,0,0}; \
  _Pragma("unroll") \
  for (int rg=0; rg<4; ++rg){ \
    float Ct = 0.f; \
    if (PASS>=2){ u32 wb = (rg<2)? NV1.x : NV1.y; Ct = bf2f((u16)(wb >> ((rg&1)*16))) * rv1[rg]; } \
    if (PASS==3){ u32 wb = (rg<2)? NV2.x : NV2.y; Ct += bf2f((u16)(wb >> ((rg&1)*16))) * rv2[rg]; } \
    float rr = fsig(giA0[rg] + ghr[rg]); \
    float zz = fsig(giA1[rg] + ghz[rg] + Ct); \
    float nn = ftanh(giA2[rg] + rr*ghn[rg]); \
    float hvv = nn + zz*(hprev[rg]-nn); \
    hprev[rg] = hvv; \
    if (PASS<=2){ \
      u32 nb = f2bf(nn); \
      if (rg==0) np0 |= nb; else if (rg==1) np0 |= nb<<16; else if (rg==2) np1 |= nb; else np1 |= nb<<16; \
    } \
    u16 hb = f2bf(hvv); \
    hHn[rg] = (short)hb; \
    hLn[rg] = (short)f2bf(hvv - bf2f(hb)); \
  } \
  if (PASS<=2){ uint2 stv; stv.x=np0; stv.y=np1; *(uint2*)(Nw + nbase + (size_t)(tt)*2048) = stv; } \
  hH = hHn; hL = hLn; \
}

  LOADA(0);
  for (int t=0; t<48; t+=2){
    LOADB(t+1);
    GRU_STEP(t,   A0,A1,A2,A3, AN1,AN2);
    LOADA(t+2);
    GRU_STEP(t+1, Bb0,Bb1,Bb2,Bb3, BN1,BN2);
  }
  LOADB(49);
  GRU_STEP(48, A0,A1,A2,A3, AN1,AN2);
  GRU_STEP(49, Bb0,Bb1,Bb2,Bb3, BN1,BN2);
#undef GRU_STEP
#undef LOADA
#undef LOADB

  float4 stv; stv.x=hprev[0]; stv.y=hprev[1]; stv.z=hprev[2]; stv.w=hprev[3];
  *(float4*)(behE + (((size_t)b*64 + k)*4 + m)*16 + j0) = stv;
}

// ---------------- softmax(b)+v+v_ (parallel softmax, 4 threads/row); vBp written directly ----------------
__global__ __launch_bounds__(256) void k_cv(const float* __restrict__ bmat, const float* __restrict__ behE,
  const float* __restrict__ W, const float* __restrict__ alpha, const float* __restrict__ wv,
  const float* __restrict__ bias, float* __restrict__ vout, u32* __restrict__ vBp)
{
  __shared__ float cm[64][65];
  __shared__ float vsh[64][17];
  __shared__ float besh[4096];
  __shared__ float smx[4][64], ssm[4][64];
  int b = blockIdx.x, tid = threadIdx.x;
  for (int it=0; it<16; ++it){
    int li = tid + it*256;
    cm[li>>6][li&63] = bmat[(size_t)b*4096 + li];
    besh[li] = behE[(size_t)b*4096 + li];
  }
  __syncthreads();
  {
    int row = tid & 63, sl = tid >> 6;
    int c0 = sl*16;
    float mx = -1e30f;
    #pragma unroll
    for (int c=0;c<16;c++) mx = fmaxf(mx, cm[row][c0+c]);
    smx[sl][row] = mx;
    __syncthreads();
    float m4 = fmaxf(fmaxf(smx[0][row],smx[1][row]), fmaxf(smx[2][row],smx[3][row]));
    float sm = 0.f;
    #pragma unroll
    for (int c=0;c<16;c++){ float e = fexp(cm[row][c0+c]-m4); cm[row][c0+c]=e; sm+=e; }
    ssm[sl][row] = sm;
    __syncthreads();
    float inv = 1.0f/(ssm[0][row]+ssm[1][row]+ssm[2][row]+ssm[3][row]);
    #pragma unroll
    for (int c=0;c<16;c++) cm[row][c0+c] *= inv;
  }
  __syncthreads();
  int j = tid & 63, dq = tid>>6;
  float a0=0,a1=0,a2=0,a3=0;
  for (int i=0;i<64;++i){
    float cij = cm[i][j];
    #pragma unroll
    for (int q=0;q<4;++q){
      int d = dq*4+q;
      const float* wp = W + ((size_t)((i*16+d)*4))*64 + j;
      float uu = besh[i*64+d]*wp[0] + besh[i*64+16+d]*wp[64]
               + besh[i*64+32+d]*wp[128] + besh[i*64+48+d]*wp[192];
      float cu = cij*uu;
      if (q==0) a0 += cu; else if (q==1) a1 += cu; else if (q==2) a2 += cu; else a3 += cu;
    }
  }
  float al = alpha[0];
  a0*=al; a1*=al; a2*=al; a3*=al;
  vsh[j][dq*4]=a0; vsh[j][dq*4+1]=a1; vsh[j][dq*4+2]=a2; vsh[j][dq*4+3]=a3;
  float* vp = vout + ((size_t)b*64 + j)*16 + dq*4;
  vp[0]=a0; vp[1]=a1; vp[2]=a2; vp[3]=a3;
  __syncthreads();
  if (tid < 64){
    float s=0.f;
    #pragma unroll
    for (int dd=0; dd<16; ++dd){ float q = vsh[tid][dd]; s += q*q; }
    float val = sqrtf(s)*wv[tid] + bias[tid];
    u16 h = f2bf(val); u16 l = f2bf(val - bf2f(h));
    vBp[b*64 + tid] = (u32)h | ((u32)l<<16);
  }
}

// ---------------- fused logits+exp+p via MFMA (split-bf16), private per-block partials ----------------
__global__ __launch_bounds__(256) void k_pfused(const u32* __restrict__ vBp, const float* __restrict__ E,
  float* __restrict__ partial)
{
  __shared__ u16 etAh[32*72], etAl[32*72];     // [item][c] pad 72
  __shared__ u16 etBh[64*32], etBl[64*32];     // [c/d][item]
  __shared__ u32 exT[128*36];                  // [b][item] packed h|l, pad 36
  int tid = threadIdx.x, lane = tid&63, w = tid>>6;
  int n16 = lane&15, quad = lane>>4;

  // preload v B-fragments (constant over items)
  short8 vh[2][2], vl[2][2];
  #pragma unroll
  for (int nt2=0; nt2<2; ++nt2){
    int b = (2*w+nt2)*16 + n16;
    #pragma unroll
    for (int s=0; s<2; ++s){
      u32 tmp[8];
      const u32* src = vBp + b*64 + s*32 + quad*8;
      #pragma unroll
      for (int q=0;q<8;q++) tmp[q]=src[q];
      unpack8(tmp, vh[nt2][s], vl[nt2][s]);
    }
  }
  f32x4 pacc[2][4];
  #pragma unroll
  for (int a2=0;a2<2;a2++)
    #pragma unroll
    for (int b2=0;b2<4;b2++){ pacc[a2][b2][0]=0.f; pacc[a2][b2][1]=0.f; pacc[a2][b2][2]=0.f; pacc[a2][b2][3]=0.f; }
  float srun[2] = {0.f, 0.f};

  int start = blockIdx.x*CHUNK3;
  int bend = start + CHUNK3; if (bend > NIT) bend = NIT;
  int sitem = tid>>3, sc0 = (tid&7)*8;
  for (int ch=0; ch<NCH3; ++ch){
    int i0 = start + ch*32;
    if (i0 >= bend) break;
    // ---- stage 32-item E tile ----
    {
      int gidx = i0 + sitem;
      float vals[8];
      if (gidx < NIT){
        float4 a = ((const float4*)E)[(size_t)gidx*16 + (sc0>>2)];
        float4 b2 = ((const float4*)E)[(size_t)gidx*16 + (sc0>>2) + 1];
        vals[0]=a.x; vals[1]=a.y; vals[2]=a.z; vals[3]=a.w;
        vals[4]=b2.x; vals[5]=b2.y; vals[6]=b2.z; vals[7]=b2.w;
      } else {
        #pragma unroll
        for (int q=0;q<8;q++) vals[q]=0.f;
      }
      u16 hh[8], ll[8];
      #pragma unroll
      for (int q=0;q<8;q++){ hh[q]=f2bf(vals[q]); ll[q]=f2bf(vals[q]-bf2f(hh[q])); }
      *(short8*)(etAh + sitem*72 + sc0) = *(short8*)hh;
      *(short8*)(etAl + sitem*72 + sc0) = *(short8*)ll;
      #pragma unroll
      for (int q=0;q<8;q++){
        etBh[(sc0+q)*32 + sitem] = hh[q];
        etBl[(sc0+q)*32 + sitem] = ll[q];
      }
    }
    __syncthreads();
    // ---- GEMM1: logits[item][b], exp, write exT ----
    short8 Eh[2][2], El[2][2];
    #pragma unroll
    for (int mt=0; mt<2; ++mt)
      #pragma unroll
      for (int s=0; s<2; ++s){
        Eh[mt][s] = *(const short8*)(etAh + (mt*16 + n16)*72 + s*32 + quad*8);
        El[mt][s] = *(const short8*)(etAl + (mt*16 + n16)*72 + s*32 + quad*8);
      }
    #pragma unroll
    for (int mt=0; mt<2; ++mt){
      #pragma unroll
      for (int nt2=0; nt2<2; ++nt2){
        f32x4 a = {0.f,0.f,0.f,0.f};
        #pragma unroll
        for (int s=0; s<2; ++s){
          a = __builtin_amdgcn_mfma_f32_16x16x32_bf16(Eh[mt][s], vh[nt2][s], a, 0,0,0);
          a = __builtin_amdgcn_mfma_f32_16x16x32_bf16(Eh[mt][s], vl[nt2][s], a, 0,0,0);
          a = __builtin_amdgcn_mfma_f32_16x16x32_bf16(El[mt][s], vh[nt2][s], a, 0,0,0);
        }
        u32 packed[4];
        #pragma unroll
        for (int rg=0; rg<4; ++rg){
          int it_g = i0 + mt*16 + quad*4 + rg;
          float ex = (it_g < bend)? fexp(a[rg]) : 0.f;
          srun[nt2] += ex;
          u16 h = f2bf(ex); u16 l = f2bf(ex - bf2f(h));
          packed[rg] = (u32)h | ((u32)l<<16);
        }
        int bl = (2*w+nt2)*16 + n16;
        uint4 st; st.x=packed[0]; st.y=packed[1]; st.z=packed[2]; st.w=packed[3];
        *(uint4*)(exT + bl*36 + mt*16 + quad*4) = st;
      }
    }
    __syncthreads();
    // ---- GEMM2: p[b][d] += exp @ E ----
    short8 Xh[2], Xl[2];
    #pragma unroll
    for (int mt2=0; mt2<2; ++mt2){
      int bl = (2*w+mt2)*16 + n16;
      uint4 t0 = *(const uint4*)(exT + bl*36 + quad*8);
      uint4 t1 = *(const uint4*)(exT + bl*36 + quad*8 + 4);
      u32 tmp[8] = {t0.x,t0.y,t0.z,t0.w,t1.x,t1.y,t1.z,t1.w};
      unpack8(tmp, Xh[mt2], Xl[mt2]);
    }
    #pragma unroll
    for (int nt3=0; nt3<4; ++nt3){
      int d = nt3*16 + n16;
      short8 Bh = *(const short8*)(etBh + d*32 + quad*8);
      short8 Bl = *(const short8*)(etBl + d*32 + quad*8);
      #pragma unroll
      for (int mt2=0; mt2<2; ++mt2){
        pacc[mt2][nt3] = __builtin_amdgcn_mfma_f32_16x16x32_bf16(Xh[mt2], Bh, pacc[mt2][nt3], 0,0,0);
        pacc[mt2][nt3] = __builtin_amdgcn_mfma_f32_16x16x32_bf16(Xh[mt2], Bl, pacc[mt2][nt3], 0,0,0);
        pacc[mt2][nt3] = __builtin_amdgcn_mfma_f32_16x16x32_bf16(Xl[mt2], Bh, pacc[mt2][nt3], 0,0,0);
      }
    }
    __syncthreads();
  }
  // ---- epilogue: private partial slice ----
  float* dst = partial + (size_t)blockIdx.x*PSTRIDE;
  #pragma unroll
  for (int mt2=0; mt2<2; ++mt2)
    #pragma unroll
    for (int nt3=0; nt3<4; ++nt3)
      #pragma unroll
      for (int rg=0; rg<4; ++rg){
        int b_g = (2*w+mt2)*16 + quad*4 + rg;
        int d_g = nt3*16 + n16;
        dst[b_g*64 + d_g] = pacc[mt2][nt3][rg];
      }
  #pragma unroll
  for (int nt2=0; nt2<2; ++nt2){
    float vsum = srun[nt2];
    vsum += __shfl_xor(vsum, 16);
    vsum += __shfl_xor(vsum, 32);
    if (quad == 0) dst[8192 + (2*w+nt2)*16 + n16] = vsum;
  }
}

// ---------------- parallel combine: 256 blocks, 8-way q-split + LDS reduce ----------------
__global__ __launch_bounds__(256) void k_pcomb(const float* __restrict__ partial, float* __restrict__ p)
{
  __shared__ float as_[8][33], ss_[8][33];
  int il = threadIdx.x & 31, qg = threadIdx.x >> 5;
  int id = blockIdx.x*32 + il;      // 256 blocks x 32 ids = 8192
  int b = id >> 6;
  float a = 0.f, s = 0.f;
  for (int q=qg; q<NBP3; q+=8){
    a += partial[(size_t)q*PSTRIDE + id];
    s += partial[(size_t)q*PSTRIDE + 8192 + b];
  }
  as_[qg][il] = a; ss_[qg][il] = s;
  __syncthreads();
  if (qg == 0){
    float at=0.f, st=0.f;
    #pragma unroll
    for (int g=0; g<8; ++g){ at += as_[g][il]; st += ss_[g][il]; }
    p[id] = at/st;
  }
}

// ---------------- r[b][j][l] = sum_d cat(p,v)[b,j,d]*Wc[j][d][l] ----------------
__global__ __launch_bounds__(256) void k_r(const float* __restrict__ p, const float* __restrict__ v,
  const float* __restrict__ Wc, float* __restrict__ r, float* __restrict__ rT)
{
  int gid = blockIdx.x*256 + threadIdx.x;
  int l = gid & 15, j = (gid>>4)&63, b = gid>>10;
  const float* wc = Wc + ((size_t)j*80)*16 + l;
  const float* pbp = p + b*64;
  float acc = 0.f;
  #pragma unroll 8
  for (int d=0; d<64; ++d) acc += pbp[d]*wc[d*16];
  const float* vb = v + ((size_t)b*64 + j)*16;
  #pragma unroll
  for (int d=0; d<16; ++d) acc += vb[d]*wc[(64+d)*16];
  r[((size_t)b*64+j)*16 + l] = acc;
  rT[((size_t)b*16+l)*64 + j] = acc;
}

// ---------------- b[b][i][j] += sum_d u[b][i][d][j]*r[b][j][d], u recomputed ----------------
__global__ __launch_bounds__(256) void k_bupd(const float* __restrict__ behE, const float* __restrict__ W,
  const float* __restrict__ rT, float* __restrict__ bmat)
{
  int lane = threadIdx.x & 63;
  int idx = blockIdx.x*4 + (threadIdx.x>>6);
  int b = idx >> 6, i = idx & 63;
  const float* be = behE + (size_t)idx*64;
  const float* rp = rT + (size_t)b*1024;
  float acc = 0.f;
  #pragma unroll
  for (int d=0; d<16; ++d){
    const float* wp = W + ((size_t)((i*16+d)*4))*64 + lane;
    float uu = be[d]*wp[0] + be[16+d]*wp[64] + be[32+d]*wp[128] + be[48+d]*wp[192];
    acc += uu * rp[d*64 + lane];
  }
  bmat[(size_t)idx*64 + lane] += acc;
}

// ---------------- final logits via MFMA (split-bf16), coalesced out[b][i] ----------------
__global__ __launch_bounds__(256) void k_logits(const u32* __restrict__ vBp, const float* __restrict__ E,
  float* __restrict__ out)
{
  __shared__ u16 etAh[64*72], etAl[64*72];   // [item][c] pad 72
  __shared__ float lt[128*68];               // [b][item] pad 68
  int tid = threadIdx.x, lane = tid&63, w = tid>>6;
  int n16 = lane&15, quad = lane>>4;
  // preload v B-fragments
  short8 vh[2][2], vl[2][2];
  #pragma unroll
  for (int nt2=0; nt2<2; ++nt2){
    int b = (2*w+nt2)*16 + n16;
    #pragma unroll
    for (int s=0; s<2; ++s){
      u32 tmp[8];
      const u32* src = vBp + b*64 + s*32 + quad*8;
      #pragma unroll
      for (int q=0;q<8;q++) tmp[q]=src[q];
      unpack8(tmp, vh[nt2][s], vl[nt2][s]);
    }
  }
  int i0 = blockIdx.x*64;
  // stage 64 items
  {
    int sitem = tid>>2, sc0 = (tid&3)*16;
    int gidx = i0 + sitem;
    float vals[16];
    if (gidx < NIT){
      #pragma unroll
      for (int q=0;q<4;q++){
        float4 a = ((const float4*)E)[(size_t)gidx*16 + (sc0>>2) + q];
        vals[4*q]=a.x; vals[4*q+1]=a.y; vals[4*q+2]=a.z; vals[4*q+3]=a.w;
      }
    } else {
      #pragma unroll
      for (int q=0;q<16;q++) vals[q]=0.f;
    }
    u16 hh[16], ll[16];
    #pragma unroll
    for (int q=0;q<16;q++){ hh[q]=f2bf(vals[q]); ll[q]=f2bf(vals[q]-bf2f(hh[q])); }
    *(short8*)(etAh + sitem*72 + sc0)     = *(short8*)hh;
    *(short8*)(etAh + sitem*72 + sc0 + 8) = *(short8*)(hh+8);
    *(short8*)(etAl + sitem*72 + sc0)     = *(short8*)ll;
    *(short8*)(etAl + sitem*72 + sc0 + 8) = *(short8*)(ll+8);
  }
  __syncthreads();
  #pragma unroll
  for (int mt=0; mt<4; ++mt){
    short8 Eh[2], El[2];
    #pragma unroll
    for (int s=0; s<2; ++s){
      Eh[s] = *(const short8*)(etAh + (mt*16 + n16)*72 + s*32 + quad*8);
      El[s] = *(const short8*)(etAl + (mt*16 + n16)*72 + s*32 + quad*8);
    }
    #pragma unroll
    for (int nt2=0; nt2<2; ++nt2){
      f32x4 a = {0.f,0.f,0.f,0.f};
      #pragma unroll
      for (int s=0; s<2; ++s){
        a = __builtin_amdgcn_mfma_f32_16x16x32_bf16(Eh[s], vh[nt2][s], a, 0,0,0);
        a = __builtin_amdgcn_mfma_f32_16x16x32_bf16(Eh[s], vl[nt2][s], a, 0,0,0);
        a = __builtin_amdgcn_mfma_f32_16x16x32_bf16(El[s], vh[nt2][s], a, 0,0,0);
      }
      int b = (2*w+nt2)*16 + n16;
      *(float4*)(lt + b*68 + mt*16 + quad*4) = *(float4*)&a;
    }
  }
  __syncthreads();
  int col = tid & 63, rgp = tid >> 6;
  if (i0 + col < NIT){
    #pragma unroll
    for (int rr=0; rr<32; ++rr){
      int b = rgp*32 + rr;
      out[(size_t)b*NIT + i0 + col] = lt[b*68 + col];
    }
  }
}

extern "C" void kernel_launch(void* const* d_in, const int* in_sizes, int n_in,
                              void* d_out, int out_size, void* d_ws, size_t ws_size,
                              hipStream_t stream)
{
  (void)in_sizes; (void)n_in; (void)out_size; (void)ws_size;
  const int*   s0 = (const int*)d_in[0];
  const int*   s1 = (const int*)d_in[1];
  const int*   s2 = (const int*)d_in[2];
  const int*   s3 = (const int*)d_in[3];
  const float* E  = (const float*)d_in[4];
  const float* W  = (const float*)d_in[5];
  const float* Wc = (const float*)d_in[6];
  const float* alpha = (const float*)d_in[7];
  const float* wv    = (const float*)d_in[8];
  const float* bias  = (const float*)d_in[9];
  const float* Wx = (const float*)d_in[10];
  const float* bx = (const float*)d_in[11];
  const float* Wh = (const float*)d_in[12];
  const float* bh = (const float*)d_in[13];

  char* ws = (char*)d_ws;
  size_t off = 0;
  auto alloc = [&](size_t bytes)->void*{ void* q = ws + off; off += (bytes + 255) & ~(size_t)255; return q; };
  u16*   N1   = (u16*)  alloc((size_t)M_*K_*T_*B_*16*2);   // 52.4 MB
  u16*   N2   = (u16*)  alloc((size_t)M_*K_*T_*B_*16*2);   // 52.4 MB
  u16*   xh   = (u16*)  alloc((size_t)M_*6400*64*2);
  u16*   xl   = (u16*)  alloc((size_t)M_*6400*64*2);
  u16*   wh   = (u16*)  alloc((size_t)M_*3072*64*2);
  u16*   wl   = (u16*)  alloc((size_t)M_*3072*64*2);
  float* bmat = (float*)alloc((size_t)B_*64*64*4);
  float* behE = (float*)alloc((size_t)B_*64*4*16*4);
  float* v    = (float*)alloc((size_t)B_*64*16*4);
  u32*   vBp  = (u32*)  alloc((size_t)128*64*4);
  float* r1   = (float*)alloc((size_t)B_*64*16*4);
  float* rT1  = (float*)alloc((size_t)B_*64*16*4);
  float* r2   = (float*)alloc((size_t)B_*64*16*4);
  float* rT2  = (float*)alloc((size_t)B_*64*16*4);
  float* p    = (float*)alloc((size_t)B_*64*4);
  float* partial = (float*)alloc((size_t)NBP3*PSTRIDE*4); // 17 MB
  // total ~140 MB

  hipMemsetAsync(bmat, 0, (size_t)B_*64*64*4, stream);
  k_prep_x<<<800,256,0,stream>>>(s0,s1,s2,s3,E,xh,xl);
  k_prep_w<<<192,256,0,stream>>>(Wx,wh,wl);

  // ---- routing iteration 1: C=0, write N1 ----
  k_gru_mfma<1><<<512,256,0,stream>>>(xh,xl,wh,wl,Wh,bx,bh,
                                      nullptr,nullptr,nullptr,nullptr, N1, behE);
  k_cv<<<128,256,0,stream>>>(bmat,behE,W,alpha,wv,bias,v,vBp);
  k_pfused<<<NBP3,256,0,stream>>>(vBp,E,partial);
  k_pcomb<<<256,256,0,stream>>>(partial,p);
  k_r<<<512,256,0,stream>>>(p,v,Wc,r1,rT1);
  k_bupd<<<2048,256,0,stream>>>(behE,W,rT1,bmat);

  // ---- routing iteration 2: C = N1*r1, write N2 ----
  k_gru_mfma<2><<<512,256,0,stream>>>(xh,xl,wh,wl,Wh,bx,bh,
                                      r1,nullptr, N1,nullptr, N2, behE);
  k_cv<<<128,256,0,stream>>>(bmat,behE,W,alpha,wv,bias,v,vBp);
  k_pfused<<<NBP3,256,0,stream>>>(vBp,E,partial);
  k_pcomb<<<256,256,0,stream>>>(partial,p);
  k_r<<<512,256,0,stream>>>(p,v,Wc,r2,rT2);
  k_bupd<<<2048,256,0,stream>>>(behE,W,rT2,bmat);

  // ---- final pass: C = N1*r1 + N2*r2 ----
  k_gru_mfma<3><<<512,256,0,stream>>>(xh,xl,wh,wl,Wh,bx,bh,
                                      r1,r2, N1,N2, nullptr, behE);
  k_cv<<<128,256,0,stream>>>(bmat,behE,W,alpha,wv,bias,v,vBp);
  k_logits<<<1563,256,0,stream>>>(vBp,E,(float*)d_out);
}